// Round 3
// baseline (742.180 us; speedup 1.0000x reference)
//
#include <hip/hip_runtime.h>

#define DIM    512
#define KCODES 8192
#define NROWS  16384
#define NEG_INF -3.402823466e38f
#define MARGIN 1.0f            // on score = dot - e_sq/2 scale; err std ~0.07
#define CAND_PER_ROW 64

typedef unsigned short ushort_t;
typedef unsigned int uint_t;
typedef __attribute__((ext_vector_type(8))) short v8s;
typedef __attribute__((ext_vector_type(4))) float v4f;

__device__ inline ushort_t f32_to_bf16_rne(float f) {
    uint_t u = __float_as_uint(f);
    uint_t r = u + 0x7fffu + ((u >> 16) & 1u);
    return (ushort_t)(r >> 16);
}

__device__ inline int4 cvt8hi(float4 a, float4 b) {
    ushort_t h[8] = { f32_to_bf16_rne(a.x), f32_to_bf16_rne(a.y),
                      f32_to_bf16_rne(a.z), f32_to_bf16_rne(a.w),
                      f32_to_bf16_rne(b.x), f32_to_bf16_rne(b.y),
                      f32_to_bf16_rne(b.z), f32_to_bf16_rne(b.w) };
    int4 p;
    p.x = (int)((uint_t)h[0] | ((uint_t)h[1] << 16));
    p.y = (int)((uint_t)h[2] | ((uint_t)h[3] << 16));
    p.z = (int)((uint_t)h[4] | ((uint_t)h[5] << 16));
    p.w = (int)((uint_t)h[6] | ((uint_t)h[7] << 16));
    return p;
}

__device__ inline void dma16(const void* g, void* l) {
    __builtin_amdgcn_global_load_lds(
        (const __attribute__((address_space(1))) unsigned int*)g,
        (__attribute__((address_space(3))) unsigned int*)l, 16, 0, 0);
}

// --------- kernel 0: bf16 conversion + norms --------------------------------
// e rows -> e_hi (ws), e_sq, esqh = -e_sq/2.  x rows -> x_hi (in d_out!), f_sq.
__global__ __launch_bounds__(256) void convert_kernel(
    const float* __restrict__ x, const float* __restrict__ embed,
    ushort_t* __restrict__ e_hi, float* __restrict__ e_sq,
    float* __restrict__ esqh, ushort_t* __restrict__ x_hi,
    float* __restrict__ f_sq)
{
    int g = blockIdx.x * 4 + (threadIdx.x >> 6);
    int lane = threadIdx.x & 63;
    bool isE = g < KCODES;
    int r = isE ? g : g - KCODES;
    const float4* src = (const float4*)((isE ? embed : x) + (size_t)r * DIM + lane * 8);
    float4 a = src[0], b = src[1];
    int4 hi = cvt8hi(a, b);
    ushort_t* dst = (isE ? e_hi : x_hi) + (size_t)r * DIM + lane * 8;
    *(int4*)dst = hi;
    float s = a.x*a.x + a.y*a.y + a.z*a.z + a.w*a.w
            + b.x*b.x + b.y*b.y + b.z*b.z + b.w*b.w;
    #pragma unroll
    for (int off = 32; off >= 1; off >>= 1) s += __shfl_down(s, off, 64);
    if (lane == 0) {
        if (isE) { e_sq[r] = s; esqh[r] = -0.5f * s; }
        else     { f_sq[r] = s; }
    }
}

// --------- kernel 1: bf16 MFMA screen, acc seeded with -e_sq/2 --------------
// Grid: 256 blocks = 64 row-tiles x 4 code-splits. 1 block/CU, 4 waves.
// Block tile: 256 codes (chunk) x 256 rows; wave tile 128x128 (acc 8x8x4).
// K-loop: 64 flat slabs (8 chunks x 8 slabs of 64k), double-buffered LDS,
// one barrier per slab, next-slab global_load_lds issued right after it.
__global__ __launch_bounds__(256, 1) void screen_kernel(
    const ushort_t* __restrict__ e_hi, const ushort_t* __restrict__ x_hi,
    const float* __restrict__ esqh,
    float* __restrict__ cand_s, int* __restrict__ cand_i)
{
    __shared__ __align__(16) short EH[2][8][256][8];
    __shared__ __align__(16) short XH[2][8][256][8];

    const int t = threadIdx.x;
    const int w = t >> 6;
    const int lane = t & 63;
    const int quad = lane >> 4;
    const int l15 = lane & 15;
    const int wm = w & 1;          // code half (128)
    const int wn = w >> 1;         // row half (128)

    const int split = blockIdx.x & 3;
    const int row0 = (blockIdx.x >> 2) * 256;
    const int cbase = split * 2048;

    // per-lane DMA source bases (each wave stages 64 codes / 64 rows)
    const ushort_t* ebase = e_hi + (size_t)(cbase + w * 64 + lane) * DIM;
    const ushort_t* xbase = x_hi + (size_t)(row0 + w * 64 + lane) * DIM;

    v4f acc[8][8];
    float b1[8], b2[8];
    int   i1[8], i2[8];
    #pragma unroll
    for (int nj = 0; nj < 8; ++nj) { b1[nj] = NEG_INF; b2[nj] = NEG_INF; i1[nj] = 0; i2[nj] = 0; }

    // seed chunk 0: acc[mi][nj][r] = -e_sq/2 of code (chunk-local wm*128+mi*16+quad*4+r)
    #pragma unroll
    for (int mi = 0; mi < 8; ++mi) {
        float4 sd = *(const float4*)(esqh + cbase + wm * 128 + mi * 16 + quad * 4);
        v4f sv = (v4f){sd.x, sd.y, sd.z, sd.w};
        #pragma unroll
        for (int nj = 0; nj < 8; ++nj) acc[mi][nj] = sv;
    }

    // issue DMA for slab S into buf S&1
    auto issue_dma = [&](int S) {
        int buf = S & 1, chunk = S >> 3, slab = S & 7;
        const ushort_t* ep = ebase + (size_t)chunk * 256 * DIM + slab * 64;
        const ushort_t* xp = xbase + slab * 64;
        #pragma unroll
        for (int q = 0; q < 8; ++q) {
            dma16(ep + q * 8, &EH[buf][q][w * 64][0]);
            dma16(xp + q * 8, &XH[buf][q][w * 64][0]);
        }
    };

    issue_dma(0);

    for (int S = 0; S < 64; ++S) {
        __syncthreads();              // drains DMA(S); DMA(S+1) issued below overlaps compute
        if (S < 63) issue_dma(S + 1);
        const int buf = S & 1;

        #pragma unroll
        for (int ks = 0; ks < 2; ++ks) {
            const int q = ks * 4 + quad;
            v8s bh[8];
            #pragma unroll
            for (int nj = 0; nj < 8; ++nj)
                bh[nj] = *(const v8s*)(&XH[buf][q][wn * 128 + nj * 16 + l15][0]);
            #pragma unroll
            for (int mi = 0; mi < 8; ++mi) {
                v8s ah = *(const v8s*)(&EH[buf][q][wm * 128 + mi * 16 + l15][0]);
                #pragma unroll
                for (int nj = 0; nj < 8; ++nj)
                    acc[mi][nj] = __builtin_amdgcn_mfma_f32_16x16x32_bf16(ah, bh[nj], acc[mi][nj], 0, 0, 0);
            }
        }

        if ((S & 7) == 7) {
            const int chunk = S >> 3;
            // epilogue: group-8 max (mi-pair cell) -> top-2 of groups per (lane,nj)
            #pragma unroll
            for (int g = 0; g < 4; ++g) {
                int gid = cbase + chunk * 256 + wm * 128 + g * 32 + quad * 4; // codes gid+{0..3,16..19}
                #pragma unroll
                for (int nj = 0; nj < 8; ++nj) {
                    v4f s0 = acc[2 * g][nj], s1 = acc[2 * g + 1][nj];
                    float m = fmaxf(fmaxf(fmaxf(s0[0], s0[1]), fmaxf(s0[2], s0[3])),
                                    fmaxf(fmaxf(s1[0], s1[1]), fmaxf(s1[2], s1[3])));
                    bool gt1 = m > b1[nj];
                    bool gt2 = m > b2[nj];
                    b2[nj] = fmaxf(fminf(m, b1[nj]), b2[nj]);   // med3
                    i2[nj] = gt1 ? i1[nj] : (gt2 ? gid : i2[nj]);
                    b1[nj] = fmaxf(b1[nj], m);
                    i1[nj] = gt1 ? gid : i1[nj];
                }
            }
            // reseed acc for next chunk
            if (S < 63) {
                #pragma unroll
                for (int mi = 0; mi < 8; ++mi) {
                    float4 sd = *(const float4*)(esqh + cbase + (chunk + 1) * 256 + wm * 128 + mi * 16 + quad * 4);
                    v4f sv = (v4f){sd.x, sd.y, sd.z, sd.w};
                    #pragma unroll
                    for (int nj = 0; nj < 8; ++nj) acc[mi][nj] = sv;
                }
            }
        }
    }

    // write candidates: 16 slots/row per split (wm x quad x top2)
    #pragma unroll
    for (int nj = 0; nj < 8; ++nj) {
        int row = row0 + wn * 128 + nj * 16 + l15;
        int slot = split * 16 + wm * 8 + quad * 2;
        size_t b = (size_t)row * CAND_PER_ROW + slot;
        cand_s[b]     = b1[nj];  cand_i[b]     = i1[nj];
        cand_s[b + 1] = b2[nj];  cand_i[b + 1] = i2[nj];
    }
}

// --------- kernel 2: exact fp32 rescore of surviving groups + gather --------
__global__ __launch_bounds__(256) void rescore_kernel(
    const float* __restrict__ x, const float* __restrict__ embed,
    const float* __restrict__ e_sq, const float* __restrict__ f_sq,
    const float* __restrict__ cand_s, const int* __restrict__ cand_i,
    float* __restrict__ out)
{
    int row = blockIdx.x * 4 + (threadIdx.x >> 6);
    int lane = threadIdx.x & 63;

    float cs = cand_s[(size_t)row * CAND_PER_ROW + lane];
    int   ci = cand_i[(size_t)row * CAND_PER_ROW + lane];

    float m = cs;
    #pragma unroll
    for (int o = 32; o >= 1; o >>= 1) m = fmaxf(m, __shfl_xor(m, o, 64));

    unsigned long long mask = __ballot(cs >= m - MARGIN);

    const float4* xsrc = (const float4*)(x + (size_t)row * DIM + lane * 8);
    float4 xa = xsrc[0], xb = xsrc[1];
    float fsq = f_sq[row];

    float bd = NEG_INF;
    int   bi = 0x7fffffff;

    while (mask) {
        int p = __ffsll(mask) - 1;
        mask &= mask - 1;
        int base = __shfl(ci, p);
        #pragma unroll
        for (int e8 = 0; e8 < 8; ++e8) {
            int c = base + ((e8 >> 2) << 4) + (e8 & 3);  // {0..3, 16..19}
            const float4* er = (const float4*)(embed + (size_t)c * DIM + lane * 8);
            float4 ea = er[0], eb = er[1];
            float part = xa.x*ea.x + xa.y*ea.y + xa.z*ea.z + xa.w*ea.w
                       + xb.x*eb.x + xb.y*eb.y + xb.z*eb.z + xb.w*eb.w;
            #pragma unroll
            for (int o = 32; o >= 1; o >>= 1) part += __shfl_xor(part, o, 64);
            float d = -((fsq - 2.0f * part) + e_sq[c]);   // np rounding order
            if (d > bd || (d == bd && c < bi)) { bd = d; bi = c; }
        }
    }

    const float4* er = (const float4*)(embed + (size_t)bi * DIM + lane * 8);
    float4 qa = er[0], qb = er[1];
    float4* dst = (float4*)(out + (size_t)row * DIM + lane * 8);
    dst[0] = qa; dst[1] = qb;
    if (lane == 0) out[(size_t)NROWS * DIM + row] = (float)bi;
}

extern "C" void kernel_launch(void* const* d_in, const int* in_sizes, int n_in,
                              void* d_out, int out_size, void* d_ws, size_t ws_size,
                              hipStream_t stream)
{
    const float* x     = (const float*)d_in[0];   // [16384, 512] fp32
    const float* embed = (const float*)d_in[1];   // [8192, 512] fp32
    float* out = (float*)d_out;

    // ws layout (~17 MB)
    float* e_sq   = (float*)d_ws;                               // 8192
    float* esqh   = e_sq + KCODES;                              // 8192 (-e_sq/2)
    float* f_sq   = esqh + KCODES;                              // 16384
    float* cand_s = f_sq + NROWS;                               // 16384*64
    int*   cand_i = (int*)(cand_s + (size_t)NROWS * CAND_PER_ROW);
    ushort_t* e_hi = (ushort_t*)(cand_i + (size_t)NROWS * CAND_PER_ROW); // 8192*512 bf16

    // x_hi lives in d_out scratch (first 16.8 MB of the 33.6 MB quantize
    // region); rescore_kernel fully overwrites d_out afterwards.
    ushort_t* x_hi = (ushort_t*)d_out;

    (void)in_sizes; (void)n_in; (void)out_size; (void)ws_size;

    convert_kernel<<<(KCODES + NROWS) / 4, 256, 0, stream>>>(
        x, embed, e_hi, e_sq, esqh, x_hi, f_sq);
    screen_kernel<<<256, 256, 0, stream>>>(
        e_hi, x_hi, esqh, cand_s, cand_i);
    rescore_kernel<<<NROWS / 4, 256, 0, stream>>>(
        x, embed, e_sq, f_sq, cand_s, cand_i, out);
}

// Round 4
// 544.215 us; speedup vs baseline: 1.3638x; 1.3638x over previous
//
#include <hip/hip_runtime.h>

#define DIM    512
#define KCODES 8192
#define NROWS  16384
#define NEG_INF -3.402823466e38f
#define MARGIN 1.0f            // score = dot - e_sq/2 scale; bf16 err std ~0.07
#define CPR 128                // cand slots per row: 32 col-tiles * 2 wm * 2

typedef unsigned short ushort_t;
typedef unsigned int uint_t;
typedef __attribute__((ext_vector_type(8))) short v8s;
typedef __attribute__((ext_vector_type(4))) float v4f;

__device__ inline ushort_t f32_to_bf16_rne(float f) {
    uint_t u = __float_as_uint(f);
    uint_t r = u + 0x7fffu + ((u >> 16) & 1u);
    return (ushort_t)(r >> 16);
}

__device__ inline int4 cvt8hi(float4 a, float4 b) {
    ushort_t h[8] = { f32_to_bf16_rne(a.x), f32_to_bf16_rne(a.y),
                      f32_to_bf16_rne(a.z), f32_to_bf16_rne(a.w),
                      f32_to_bf16_rne(b.x), f32_to_bf16_rne(b.y),
                      f32_to_bf16_rne(b.z), f32_to_bf16_rne(b.w) };
    int4 p;
    p.x = (int)((uint_t)h[0] | ((uint_t)h[1] << 16));
    p.y = (int)((uint_t)h[2] | ((uint_t)h[3] << 16));
    p.z = (int)((uint_t)h[4] | ((uint_t)h[5] << 16));
    p.w = (int)((uint_t)h[6] | ((uint_t)h[7] << 16));
    return p;
}

__device__ inline void dma16(const void* g, void* l) {
    __builtin_amdgcn_global_load_lds(
        (const __attribute__((address_space(1))) unsigned int*)g,
        (__attribute__((address_space(3))) unsigned int*)l, 16, 0, 0);
}

// --------- kernel 0: bf16 conversion + norms --------------------------------
__global__ __launch_bounds__(256) void convert_kernel(
    const float* __restrict__ x, const float* __restrict__ embed,
    ushort_t* __restrict__ e_hi, float* __restrict__ e_sq,
    float* __restrict__ esqh, ushort_t* __restrict__ x_hi,
    float* __restrict__ f_sq)
{
    int g = blockIdx.x * 4 + (threadIdx.x >> 6);
    int lane = threadIdx.x & 63;
    bool isE = g < KCODES;
    int r = isE ? g : g - KCODES;
    const float4* src = (const float4*)((isE ? embed : x) + (size_t)r * DIM + lane * 8);
    float4 a = src[0], b = src[1];
    int4 hi = cvt8hi(a, b);
    ushort_t* dst = (isE ? e_hi : x_hi) + (size_t)r * DIM + lane * 8;
    *(int4*)dst = hi;
    float s = a.x*a.x + a.y*a.y + a.z*a.z + a.w*a.w
            + b.x*b.x + b.y*b.y + b.z*b.z + b.w*b.w;
    #pragma unroll
    for (int off = 32; off >= 1; off >>= 1) s += __shfl_down(s, off, 64);
    if (lane == 0) {
        if (isE) { e_sq[r] = s; esqh[r] = -0.5f * s; }
        else     { f_sq[r] = s; }
    }
}

// --------- kernel 1: bf16 MFMA screen — full-K, seed-once, epilogue-once ----
// Grid: 2048 blocks = 64 row-tiles x 32 code-cols (XCD-swizzled). 1 block/CU.
// Block tile: 256 codes x 256 rows x K=512; wave tile 128x128 (acc 8x8x4,
// AGPR-resident: K-loop touches acc only via MFMA). 8 slabs of 64-k, dbuf
// LDS (128 KB), ONE barrier per slab, next-slab DMA issued right after it.
__global__ __launch_bounds__(256, 1) void screen_kernel(
    const ushort_t* __restrict__ e_hi, const ushort_t* __restrict__ x_hi,
    const float* __restrict__ esqh,
    float* __restrict__ cand_s, int* __restrict__ cand_i)
{
    __shared__ __align__(16) short EH[2][8][256][8];   // 64 KB
    __shared__ __align__(16) short XH[2][8][256][8];   // 64 KB

    const int t = threadIdx.x;
    const int w = t >> 6;
    const int lane = t & 63;
    const int quad = lane >> 4;
    const int l15 = lane & 15;
    const int wm = w & 1;          // code half (128)
    const int wn = w >> 1;         // row half (128)

    // XCD swizzle: xcd = n&7 owns 8 row-tiles x 32 col-tiles.
    // Concurrent window per XCD: 8 row-tiles (X: 2 MB) + ~4 E-cols (1 MB) < 4 MB L2.
    const int n = blockIdx.x;
    const int xcd = n & 7;
    const int j = n >> 3;                 // 0..255
    const int rt = xcd * 8 + (j & 7);     // 0..63
    const int ct = j >> 3;                // 0..31
    const int row0 = rt * 256;
    const int cbase = ct * 256;

    const ushort_t* ebase = e_hi + (size_t)(cbase + w * 64 + lane) * DIM;
    const ushort_t* xbase = x_hi + (size_t)(row0 + w * 64 + lane) * DIM;

    // seed acc with -e_sq/2 (per-mi code, same for all nj) — once.
    v4f acc[8][8];
    #pragma unroll
    for (int mi = 0; mi < 8; ++mi) {
        float4 sd = *(const float4*)(esqh + cbase + wm * 128 + mi * 16 + quad * 4);
        v4f sv = (v4f){sd.x, sd.y, sd.z, sd.w};
        #pragma unroll
        for (int nj = 0; nj < 8; ++nj) acc[mi][nj] = sv;
    }

    auto issue_dma = [&](int S) {
        int buf = S & 1;
        const ushort_t* ep = ebase + S * 64;
        const ushort_t* xp = xbase + S * 64;
        #pragma unroll
        for (int q = 0; q < 8; ++q) {
            dma16(ep + q * 8, &EH[buf][q][w * 64][0]);
            dma16(xp + q * 8, &XH[buf][q][w * 64][0]);
        }
    };

    issue_dma(0);

    for (int S = 0; S < 8; ++S) {
        __syncthreads();               // drains DMA(S); DMA(S+1) overlaps compute
        if (S < 7) issue_dma(S + 1);
        const int buf = S & 1;

        #pragma unroll
        for (int ks = 0; ks < 2; ++ks) {
            const int q = ks * 4 + quad;
            v8s bh[8];
            #pragma unroll
            for (int nj = 0; nj < 8; ++nj)
                bh[nj] = *(const v8s*)(&XH[buf][q][wn * 128 + nj * 16 + l15][0]);
            #pragma unroll
            for (int mi = 0; mi < 8; ++mi) {
                v8s ah = *(const v8s*)(&EH[buf][q][wm * 128 + mi * 16 + l15][0]);
                #pragma unroll
                for (int nj = 0; nj < 8; ++nj)
                    acc[mi][nj] = __builtin_amdgcn_mfma_f32_16x16x32_bf16(ah, bh[nj], acc[mi][nj], 0, 0, 0);
            }
        }
    }

    // ---- epilogue (once): group-8 max -> top-2 of 4 -> quad merge ----------
    #pragma unroll
    for (int nj = 0; nj < 8; ++nj) {
        float b1 = NEG_INF, b2 = NEG_INF;
        int   i1 = 0, i2 = 0;
        #pragma unroll
        for (int g = 0; g < 4; ++g) {
            v4f s0 = acc[2 * g][nj], s1 = acc[2 * g + 1][nj];
            float m = fmaxf(fmaxf(fmaxf(s0[0], s0[1]), fmaxf(s0[2], s0[3])),
                            fmaxf(fmaxf(s1[0], s1[1]), fmaxf(s1[2], s1[3])));
            int gid = cbase + wm * 128 + g * 32 + quad * 4;  // codes gid+{0..3,16..19}
            if (m > b1)      { b2 = b1; i2 = i1; b1 = m; i1 = gid; }
            else if (m > b2) { b2 = m;  i2 = gid; }
        }
        #pragma unroll
        for (int o = 16; o <= 32; o <<= 1) {   // merge across the 4 quads
            float c1 = __shfl_xor(b1, o, 64);
            int   j1 = __shfl_xor(i1, o, 64);
            float c2 = __shfl_xor(b2, o, 64);
            int   j2 = __shfl_xor(i2, o, 64);
            if (c1 > b1) {
                b2 = fmaxf(b1, c2); i2 = (b1 >= c2) ? i1 : j2;
                b1 = c1; i1 = j1;
            } else {
                i2 = (b2 >= c1) ? i2 : j1;
                b2 = fmaxf(b2, c1);
            }
        }
        if (quad == 0) {
            int row = row0 + wn * 128 + nj * 16 + l15;
            size_t b = (size_t)row * CPR + (ct * 4 + wm * 2);
            cand_s[b]     = b1;  cand_i[b]     = i1;
            cand_s[b + 1] = b2;  cand_i[b + 1] = i2;
        }
    }
}

// --------- kernel 2: exact fp32 rescore of surviving groups + gather --------
__global__ __launch_bounds__(256) void rescore_kernel(
    const float* __restrict__ x, const float* __restrict__ embed,
    const float* __restrict__ e_sq, const float* __restrict__ f_sq,
    const float* __restrict__ cand_s, const int* __restrict__ cand_i,
    float* __restrict__ out)
{
    int row = blockIdx.x * 4 + (threadIdx.x >> 6);
    int lane = threadIdx.x & 63;
    size_t cb = (size_t)row * CPR;

    float cs0 = cand_s[cb + lane];
    float cs1 = cand_s[cb + 64 + lane];
    int   ci0 = cand_i[cb + lane];
    int   ci1 = cand_i[cb + 64 + lane];

    float m = fmaxf(cs0, cs1);
    #pragma unroll
    for (int o = 32; o >= 1; o >>= 1) m = fmaxf(m, __shfl_xor(m, o, 64));

    unsigned long long mask0 = __ballot(cs0 >= m - MARGIN);
    unsigned long long mask1 = __ballot(cs1 >= m - MARGIN);

    const float4* xsrc = (const float4*)(x + (size_t)row * DIM + lane * 8);
    float4 xa = xsrc[0], xb = xsrc[1];
    float fsq = f_sq[row];

    float bd = NEG_INF;
    int   bi = 0x7fffffff;

    #pragma unroll
    for (int s = 0; s < 2; ++s) {
        unsigned long long mask = s ? mask1 : mask0;
        while (mask) {
            int p = __ffsll(mask) - 1;
            mask &= mask - 1;
            int base = __shfl(s ? ci1 : ci0, p);
            #pragma unroll
            for (int e8 = 0; e8 < 8; ++e8) {
                int c = base + ((e8 >> 2) << 4) + (e8 & 3);  // {0..3, 16..19}
                const float4* er = (const float4*)(embed + (size_t)c * DIM + lane * 8);
                float4 ea = er[0], eb = er[1];
                float part = xa.x*ea.x + xa.y*ea.y + xa.z*ea.z + xa.w*ea.w
                           + xb.x*eb.x + xb.y*eb.y + xb.z*eb.z + xb.w*eb.w;
                #pragma unroll
                for (int o = 32; o >= 1; o >>= 1) part += __shfl_xor(part, o, 64);
                float d = -((fsq - 2.0f * part) + e_sq[c]);   // np rounding order
                if (d > bd || (d == bd && c < bi)) { bd = d; bi = c; }
            }
        }
    }

    const float4* er = (const float4*)(embed + (size_t)bi * DIM + lane * 8);
    float4 qa = er[0], qb = er[1];
    float4* dst = (float4*)(out + (size_t)row * DIM + lane * 8);
    dst[0] = qa; dst[1] = qb;
    if (lane == 0) out[(size_t)NROWS * DIM + row] = (float)bi;
}

extern "C" void kernel_launch(void* const* d_in, const int* in_sizes, int n_in,
                              void* d_out, int out_size, void* d_ws, size_t ws_size,
                              hipStream_t stream)
{
    const float* x     = (const float*)d_in[0];   // [16384, 512] fp32
    const float* embed = (const float*)d_in[1];   // [8192, 512] fp32
    float* out = (float*)d_out;

    // ws layout (~24.3 MB)
    float* e_sq   = (float*)d_ws;                               // 8192
    float* esqh   = e_sq + KCODES;                              // 8192 (-e_sq/2)
    float* f_sq   = esqh + KCODES;                              // 16384
    float* cand_s = f_sq + NROWS;                               // 16384*128
    int*   cand_i = (int*)(cand_s + (size_t)NROWS * CPR);       // 16384*128
    ushort_t* e_hi = (ushort_t*)(cand_i + (size_t)NROWS * CPR); // 8192*512 bf16

    // x_hi lives in d_out scratch; rescore fully overwrites d_out afterwards.
    ushort_t* x_hi = (ushort_t*)d_out;

    (void)in_sizes; (void)n_in; (void)out_size; (void)ws_size;

    convert_kernel<<<(KCODES + NROWS) / 4, 256, 0, stream>>>(
        x, embed, e_hi, e_sq, esqh, x_hi, f_sq);
    screen_kernel<<<2048, 256, 0, stream>>>(
        e_hi, x_hi, esqh, cand_s, cand_i);
    rescore_kernel<<<NROWS / 4, 256, 0, stream>>>(
        x, embed, e_sq, f_sq, cand_s, cand_i, out);
}

// Round 5
// 383.855 us; speedup vs baseline: 1.9335x; 1.4178x over previous
//
#include <hip/hip_runtime.h>

#define DIM    512
#define KCODES 8192
#define NROWS  16384
#define NEG_INF -3.402823466e38f
#define MARGIN 1.0f            // score = dot - e_sq/2 scale; bf16 err std ~0.07
#define CPR 128                // cand slots per row: 32 col-tiles * 2 wm * 2

typedef unsigned short ushort_t;
typedef unsigned int uint_t;
typedef __attribute__((ext_vector_type(8))) short v8s;
typedef __attribute__((ext_vector_type(4))) float v4f;

__device__ inline ushort_t f32_to_bf16_rne(float f) {
    uint_t u = __float_as_uint(f);
    uint_t r = u + 0x7fffu + ((u >> 16) & 1u);
    return (ushort_t)(r >> 16);
}

__device__ inline int4 cvt8hi(float4 a, float4 b) {
    ushort_t h[8] = { f32_to_bf16_rne(a.x), f32_to_bf16_rne(a.y),
                      f32_to_bf16_rne(a.z), f32_to_bf16_rne(a.w),
                      f32_to_bf16_rne(b.x), f32_to_bf16_rne(b.y),
                      f32_to_bf16_rne(b.z), f32_to_bf16_rne(b.w) };
    int4 p;
    p.x = (int)((uint_t)h[0] | ((uint_t)h[1] << 16));
    p.y = (int)((uint_t)h[2] | ((uint_t)h[3] << 16));
    p.z = (int)((uint_t)h[4] | ((uint_t)h[5] << 16));
    p.w = (int)((uint_t)h[6] | ((uint_t)h[7] << 16));
    return p;
}

__device__ inline void dma16(const void* g, void* l) {
    __builtin_amdgcn_global_load_lds(
        (const __attribute__((address_space(1))) unsigned int*)g,
        (__attribute__((address_space(3))) unsigned int*)l, 16, 0, 0);
}

// --------- kernel 0: bf16 convert + norms + k-major TRANSPOSE ---------------
// Output layouts (int4 = 8 bf16 = one 16-elem... one 8-k chunk):
//   e_t[sq][8192]  sq = k/8 in 0..63   (8 MB)
//   x_t[sq][16384]                     (16 MB, lives in d_out scratch)
// Block = 64 rows; wave w handles 16 rows. LDS transpose with XOR swizzle:
// chunk sq of local row r stored at buf[r][(sq + r) & 63].
__global__ __launch_bounds__(256) void convert_kernel(
    const float* __restrict__ x, const float* __restrict__ embed,
    int4* __restrict__ e_t, int4* __restrict__ x_t,
    float* __restrict__ e_sq, float* __restrict__ esqh,
    float* __restrict__ f_sq)
{
    __shared__ int4 buf[64][64];   // 64 KB

    const int w = threadIdx.x >> 6;
    const int lane = threadIdx.x & 63;
    const bool isE = blockIdx.x < (KCODES / 64);
    const int rows0 = isE ? blockIdx.x * 64 : (blockIdx.x - KCODES / 64) * 64;
    const float* src_base = isE ? embed : x;

    #pragma unroll
    for (int rr = 0; rr < 16; ++rr) {
        int r_local = w * 16 + rr;
        const float* src = src_base + (size_t)(rows0 + r_local) * DIM + lane * 8;
        float4 a = *(const float4*)src;
        float4 b = *(const float4*)(src + 4);
        buf[r_local][(lane + r_local) & 63] = cvt8hi(a, b);
        float s = a.x*a.x + a.y*a.y + a.z*a.z + a.w*a.w
                + b.x*b.x + b.y*b.y + b.z*b.z + b.w*b.w;
        #pragma unroll
        for (int off = 32; off >= 1; off >>= 1) s += __shfl_down(s, off, 64);
        if (lane == 0) {
            int r = rows0 + r_local;
            if (isE) { e_sq[r] = s; esqh[r] = -0.5f * s; }
            else     { f_sq[r] = s; }
        }
    }
    __syncthreads();

    #pragma unroll
    for (int i = 0; i < 16; ++i) {
        int sq = w * 16 + i;
        int4 v = buf[lane][(sq + lane) & 63];
        if (isE) e_t[(size_t)sq * KCODES + rows0 + lane] = v;
        else     x_t[(size_t)sq * NROWS  + rows0 + lane] = v;
    }
}

// --------- kernel 1: bf16 MFMA screen — full-K, seed-once, epilogue-once ----
// Grid: 2048 blocks = 64 row-tiles x 32 code-cols (XCD-swizzled). 1 block/CU.
// Block tile: 256 codes x 256 rows x K=512; wave tile 128x128 (acc 8x8x4,
// AGPR-resident). 8 slabs of 64-k, dbuf LDS (128 KB), one barrier per slab,
// next-slab DMA issued right after it. DMA sources are k-major transposed
// layouts -> every global_load_lds is a fully-coalesced 1 KB read.
__global__ __launch_bounds__(256, 1) void screen_kernel(
    const int4* __restrict__ e_t, const int4* __restrict__ x_t,
    const float* __restrict__ esqh,
    float* __restrict__ cand_s, int* __restrict__ cand_i)
{
    __shared__ __align__(16) short EH[2][8][256][8];   // 64 KB
    __shared__ __align__(16) short XH[2][8][256][8];   // 64 KB

    const int t = threadIdx.x;
    const int w = t >> 6;
    const int lane = t & 63;
    const int quad = lane >> 4;
    const int l15 = lane & 15;
    const int wm = w & 1;          // code half (128)
    const int wn = w >> 1;         // row half (128)

    const int n = blockIdx.x;
    const int xcd = n & 7;
    const int j = n >> 3;
    const int rt = xcd * 8 + (j & 7);
    const int ct = j >> 3;
    const int row0 = rt * 256;
    const int cbase = ct * 256;

    // coalesced DMA bases: lane-contiguous int4 rows in k-major layouts
    const int4* ebase = e_t + cbase + w * 64 + lane;
    const int4* xbase = x_t + row0  + w * 64 + lane;

    v4f acc[8][8];
    #pragma unroll
    for (int mi = 0; mi < 8; ++mi) {
        float4 sd = *(const float4*)(esqh + cbase + wm * 128 + mi * 16 + quad * 4);
        v4f sv = (v4f){sd.x, sd.y, sd.z, sd.w};
        #pragma unroll
        for (int nj = 0; nj < 8; ++nj) acc[mi][nj] = sv;
    }

    auto issue_dma = [&](int S) {
        int buf = S & 1;
        #pragma unroll
        for (int q = 0; q < 8; ++q) {
            int sq = S * 8 + q;
            dma16(ebase + (size_t)sq * KCODES, &EH[buf][q][w * 64][0]);
            dma16(xbase + (size_t)sq * NROWS,  &XH[buf][q][w * 64][0]);
        }
    };

    issue_dma(0);

    for (int S = 0; S < 8; ++S) {
        __syncthreads();               // drains DMA(S); DMA(S+1) overlaps compute
        if (S < 7) issue_dma(S + 1);
        const int buf = S & 1;

        #pragma unroll
        for (int ks = 0; ks < 2; ++ks) {
            const int q = ks * 4 + quad;
            v8s bh[8];
            #pragma unroll
            for (int nj = 0; nj < 8; ++nj)
                bh[nj] = *(const v8s*)(&XH[buf][q][wn * 128 + nj * 16 + l15][0]);
            #pragma unroll
            for (int mi = 0; mi < 8; ++mi) {
                v8s ah = *(const v8s*)(&EH[buf][q][wm * 128 + mi * 16 + l15][0]);
                #pragma unroll
                for (int nj = 0; nj < 8; ++nj)
                    acc[mi][nj] = __builtin_amdgcn_mfma_f32_16x16x32_bf16(ah, bh[nj], acc[mi][nj], 0, 0, 0);
            }
        }
    }

    // ---- epilogue (once): group-8 max -> top-2 of 4 -> quad merge ----------
    #pragma unroll
    for (int nj = 0; nj < 8; ++nj) {
        float b1 = NEG_INF, b2 = NEG_INF;
        int   i1 = 0, i2 = 0;
        #pragma unroll
        for (int g = 0; g < 4; ++g) {
            v4f s0 = acc[2 * g][nj], s1 = acc[2 * g + 1][nj];
            float m = fmaxf(fmaxf(fmaxf(s0[0], s0[1]), fmaxf(s0[2], s0[3])),
                            fmaxf(fmaxf(s1[0], s1[1]), fmaxf(s1[2], s1[3])));
            int gid = cbase + wm * 128 + g * 32 + quad * 4;  // codes gid+{0..3,16..19}
            if (m > b1)      { b2 = b1; i2 = i1; b1 = m; i1 = gid; }
            else if (m > b2) { b2 = m;  i2 = gid; }
        }
        #pragma unroll
        for (int o = 16; o <= 32; o <<= 1) {   // merge across the 4 quads
            float c1 = __shfl_xor(b1, o, 64);
            int   j1 = __shfl_xor(i1, o, 64);
            float c2 = __shfl_xor(b2, o, 64);
            int   j2 = __shfl_xor(i2, o, 64);
            if (c1 > b1) {
                b2 = fmaxf(b1, c2); i2 = (b1 >= c2) ? i1 : j2;
                b1 = c1; i1 = j1;
            } else {
                i2 = (b2 >= c1) ? i2 : j1;
                b2 = fmaxf(b2, c1);
            }
        }
        if (quad == 0) {
            int row = row0 + wn * 128 + nj * 16 + l15;
            size_t b = (size_t)row * CPR + (ct * 4 + wm * 2);
            cand_s[b]     = b1;  cand_i[b]     = i1;
            cand_s[b + 1] = b2;  cand_i[b + 1] = i2;
        }
    }
}

// --------- kernel 2: exact fp32 rescore of surviving groups + gather --------
__global__ __launch_bounds__(256) void rescore_kernel(
    const float* __restrict__ x, const float* __restrict__ embed,
    const float* __restrict__ e_sq, const float* __restrict__ f_sq,
    const float* __restrict__ cand_s, const int* __restrict__ cand_i,
    float* __restrict__ out)
{
    int row = blockIdx.x * 4 + (threadIdx.x >> 6);
    int lane = threadIdx.x & 63;
    size_t cb = (size_t)row * CPR;

    float cs0 = cand_s[cb + lane];
    float cs1 = cand_s[cb + 64 + lane];
    int   ci0 = cand_i[cb + lane];
    int   ci1 = cand_i[cb + 64 + lane];

    float m = fmaxf(cs0, cs1);
    #pragma unroll
    for (int o = 32; o >= 1; o >>= 1) m = fmaxf(m, __shfl_xor(m, o, 64));

    unsigned long long mask0 = __ballot(cs0 >= m - MARGIN);
    unsigned long long mask1 = __ballot(cs1 >= m - MARGIN);

    const float4* xsrc = (const float4*)(x + (size_t)row * DIM + lane * 8);
    float4 xa = xsrc[0], xb = xsrc[1];
    float fsq = f_sq[row];

    float bd = NEG_INF;
    int   bi = 0x7fffffff;

    #pragma unroll
    for (int s = 0; s < 2; ++s) {
        unsigned long long mask = s ? mask1 : mask0;
        while (mask) {
            int p = __ffsll(mask) - 1;
            mask &= mask - 1;
            int base = __shfl(s ? ci1 : ci0, p);
            #pragma unroll
            for (int e8 = 0; e8 < 8; ++e8) {
                int c = base + ((e8 >> 2) << 4) + (e8 & 3);  // {0..3, 16..19}
                const float4* er = (const float4*)(embed + (size_t)c * DIM + lane * 8);
                float4 ea = er[0], eb = er[1];
                float part = xa.x*ea.x + xa.y*ea.y + xa.z*ea.z + xa.w*ea.w
                           + xb.x*eb.x + xb.y*eb.y + xb.z*eb.z + xb.w*eb.w;
                #pragma unroll
                for (int o = 32; o >= 1; o >>= 1) part += __shfl_xor(part, o, 64);
                float d = -((fsq - 2.0f * part) + e_sq[c]);   // np rounding order
                if (d > bd || (d == bd && c < bi)) { bd = d; bi = c; }
            }
        }
    }

    const float4* er = (const float4*)(embed + (size_t)bi * DIM + lane * 8);
    float4 qa = er[0], qb = er[1];
    float4* dst = (float4*)(out + (size_t)row * DIM + lane * 8);
    dst[0] = qa; dst[1] = qb;
    if (lane == 0) out[(size_t)NROWS * DIM + row] = (float)bi;
}

extern "C" void kernel_launch(void* const* d_in, const int* in_sizes, int n_in,
                              void* d_out, int out_size, void* d_ws, size_t ws_size,
                              hipStream_t stream)
{
    const float* x     = (const float*)d_in[0];   // [16384, 512] fp32
    const float* embed = (const float*)d_in[1];   // [8192, 512] fp32
    float* out = (float*)d_out;

    // ws layout (~25 MB), all 16B-aligned
    float* e_sq   = (float*)d_ws;                               // 8192
    float* esqh   = e_sq + KCODES;                              // 8192 (-e_sq/2)
    float* f_sq   = esqh + KCODES;                              // 16384
    float* cand_s = f_sq + NROWS;                               // 16384*128
    int*   cand_i = (int*)(cand_s + (size_t)NROWS * CPR);       // 16384*128
    int4*  e_t    = (int4*)(cand_i + (size_t)NROWS * CPR);      // [64][8192] int4 = 8 MB

    // x_t lives in d_out scratch (16 MB of 33.6 MB); rescore overwrites later.
    int4* x_t = (int4*)d_out;

    (void)in_sizes; (void)n_in; (void)out_size; (void)ws_size;

    convert_kernel<<<(KCODES + NROWS) / 64, 256, 0, stream>>>(
        x, embed, e_t, x_t, e_sq, esqh, f_sq);
    screen_kernel<<<2048, 256, 0, stream>>>(
        e_t, x_t, esqh, cand_s, cand_i);
    rescore_kernel<<<NROWS / 4, 256, 0, stream>>>(
        x, embed, e_sq, f_sq, cand_s, cand_i, out);
}

// Round 6
// 272.658 us; speedup vs baseline: 2.7220x; 1.4078x over previous
//
#include <hip/hip_runtime.h>

#define DIM    512
#define KCODES 8192
#define NROWS  16384
#define NEG_INF -3.402823466e38f
#define MARGIN 1.0f            // score = dot - e_sq/2 scale; bf16 err std ~0.07
#define CPR 128                // cand slots per row: 32 col-tiles * 2 wm * 2

typedef unsigned short ushort_t;
typedef unsigned int uint_t;
typedef __attribute__((ext_vector_type(8))) short v8s;
typedef __attribute__((ext_vector_type(4))) float v4f;

__device__ inline ushort_t f32_to_bf16_rne(float f) {
    uint_t u = __float_as_uint(f);
    uint_t r = u + 0x7fffu + ((u >> 16) & 1u);
    return (ushort_t)(r >> 16);
}

__device__ inline int4 cvt8hi(float4 a, float4 b) {
    ushort_t h[8] = { f32_to_bf16_rne(a.x), f32_to_bf16_rne(a.y),
                      f32_to_bf16_rne(a.z), f32_to_bf16_rne(a.w),
                      f32_to_bf16_rne(b.x), f32_to_bf16_rne(b.y),
                      f32_to_bf16_rne(b.z), f32_to_bf16_rne(b.w) };
    int4 p;
    p.x = (int)((uint_t)h[0] | ((uint_t)h[1] << 16));
    p.y = (int)((uint_t)h[2] | ((uint_t)h[3] << 16));
    p.z = (int)((uint_t)h[4] | ((uint_t)h[5] << 16));
    p.w = (int)((uint_t)h[6] | ((uint_t)h[7] << 16));
    return p;
}

__device__ inline void dma16(const void* g, void* l) {
    __builtin_amdgcn_global_load_lds(
        (const __attribute__((address_space(1))) unsigned int*)g,
        (__attribute__((address_space(3))) unsigned int*)l, 16, 0, 0);
}

// --------- kernel 0: bf16 convert + norms + k-major TRANSPOSE ---------------
// e_t[sq][8192], x_t[sq][16384] as int4 (8 bf16 per (k-chunk sq, row)).
// LDS transpose, pad 65 + col swizzle (sq + 2r) & 63: both phases
// conflict-free (read-phase lane coefficient 67 ≡ 3 mod 8, odd).
__global__ __launch_bounds__(256) void convert_kernel(
    const float* __restrict__ x, const float* __restrict__ embed,
    int4* __restrict__ e_t, int4* __restrict__ x_t,
    float* __restrict__ e_sq, float* __restrict__ esqh,
    float* __restrict__ f_sq)
{
    __shared__ int4 buf[64][65];   // 66.6 KB

    const int w = threadIdx.x >> 6;
    const int lane = threadIdx.x & 63;
    const bool isE = blockIdx.x < (KCODES / 64);
    const int rows0 = isE ? blockIdx.x * 64 : (blockIdx.x - KCODES / 64) * 64;
    const float* src_base = isE ? embed : x;

    #pragma unroll
    for (int rr = 0; rr < 16; ++rr) {
        int r_local = w * 16 + rr;
        const float* src = src_base + (size_t)(rows0 + r_local) * DIM + lane * 8;
        float4 a = *(const float4*)src;
        float4 b = *(const float4*)(src + 4);
        buf[r_local][(lane + 2 * r_local) & 63] = cvt8hi(a, b);   // sq = lane
        float s = a.x*a.x + a.y*a.y + a.z*a.z + a.w*a.w
                + b.x*b.x + b.y*b.y + b.z*b.z + b.w*b.w;
        #pragma unroll
        for (int off = 32; off >= 1; off >>= 1) s += __shfl_down(s, off, 64);
        if (lane == 0) {
            int r = rows0 + r_local;
            if (isE) { e_sq[r] = s; esqh[r] = -0.5f * s; }
            else     { f_sq[r] = s; }
        }
    }
    __syncthreads();

    #pragma unroll
    for (int i = 0; i < 16; ++i) {
        int sq = w * 16 + i;
        int4 v = buf[lane][(sq + 2 * lane) & 63];
        if (isE) e_t[(size_t)sq * KCODES + rows0 + lane] = v;
        else     x_t[(size_t)sq * NROWS  + rows0 + lane] = v;
    }
}

// --------- kernel 1: bf16 MFMA screen — 512 thr, 8 waves, 2 waves/SIMD ------
// Grid: 2048 blocks = 64 row-tiles x 32 code-cols (XCD-swizzled). 1 block/CU.
// Block tile: 256 codes x 256 rows x K=512; wave tile 128x64 (acc 8x4x4 =
// 128 regs — fits 2 waves/SIMD at 256 regs/wave, no spill). 8 slabs of 64-k,
// dbuf LDS (128 KB), one barrier per slab, next-slab DMA right after it.
// Waves 0-3 stage EH, waves 4-7 stage XH (8 coalesced 1 KB dma16 each).
__global__ __launch_bounds__(512, 2) void screen_kernel(
    const int4* __restrict__ e_t, const int4* __restrict__ x_t,
    const float* __restrict__ esqh,
    float* __restrict__ cand_s, int* __restrict__ cand_i)
{
    __shared__ __align__(16) short EH[2][8][256][8];   // 64 KB
    __shared__ __align__(16) short XH[2][8][256][8];   // 64 KB

    const int t = threadIdx.x;
    const int w = t >> 6;          // 0..7
    const int lane = t & 63;
    const int quad = lane >> 4;
    const int l15 = lane & 15;
    const int wm = w & 1;          // code half (128)
    const int wn = w >> 1;         // row quarter (64)

    const int n = blockIdx.x;
    const int xcd = n & 7;
    const int j = n >> 3;
    const int rt = xcd * 8 + (j & 7);
    const int ct = j >> 3;
    const int row0 = rt * 256;
    const int cbase = ct * 256;

    // DMA bases: waves 0-3 -> E codes w*64, waves 4-7 -> X rows (w-4)*64
    const bool isE = w < 4;
    const int4* gbase = isE ? (e_t + cbase + w * 64 + lane)
                            : (x_t + row0 + (w - 4) * 64 + lane);
    const size_t gstride = isE ? KCODES : NROWS;

    v4f acc[8][4];
    #pragma unroll
    for (int mi = 0; mi < 8; ++mi) {
        float4 sd = *(const float4*)(esqh + cbase + wm * 128 + mi * 16 + quad * 4);
        v4f sv = (v4f){sd.x, sd.y, sd.z, sd.w};
        #pragma unroll
        for (int nj = 0; nj < 4; ++nj) acc[mi][nj] = sv;
    }

    auto issue_dma = [&](int S) {
        int buf = S & 1;
        short* ldst = isE ? &EH[buf][0][(w & 3) * 64][0] : &XH[buf][0][(w & 3) * 64][0];
        #pragma unroll
        for (int q = 0; q < 8; ++q) {
            int sq = S * 8 + q;
            dma16(gbase + (size_t)sq * gstride, ldst + q * 256 * 8);
        }
    };

    issue_dma(0);

    for (int S = 0; S < 8; ++S) {
        __syncthreads();               // drains DMA(S); DMA(S+1) overlaps compute
        if (S < 7) issue_dma(S + 1);
        const int buf = S & 1;

        #pragma unroll
        for (int ks = 0; ks < 2; ++ks) {
            const int q = ks * 4 + quad;
            v8s bh[4];
            #pragma unroll
            for (int nj = 0; nj < 4; ++nj)
                bh[nj] = *(const v8s*)(&XH[buf][q][wn * 64 + nj * 16 + l15][0]);
            #pragma unroll
            for (int mi = 0; mi < 8; ++mi) {
                v8s ah = *(const v8s*)(&EH[buf][q][wm * 128 + mi * 16 + l15][0]);
                #pragma unroll
                for (int nj = 0; nj < 4; ++nj)
                    acc[mi][nj] = __builtin_amdgcn_mfma_f32_16x16x32_bf16(ah, bh[nj], acc[mi][nj], 0, 0, 0);
            }
        }
    }

    // ---- epilogue (once): group-8 max -> top-2 of 4 -> quad merge ----------
    #pragma unroll
    for (int nj = 0; nj < 4; ++nj) {
        float b1 = NEG_INF, b2 = NEG_INF;
        int   i1 = 0, i2 = 0;
        #pragma unroll
        for (int g = 0; g < 4; ++g) {
            v4f s0 = acc[2 * g][nj], s1 = acc[2 * g + 1][nj];
            float m = fmaxf(fmaxf(fmaxf(s0[0], s0[1]), fmaxf(s0[2], s0[3])),
                            fmaxf(fmaxf(s1[0], s1[1]), fmaxf(s1[2], s1[3])));
            int gid = cbase + wm * 128 + g * 32 + quad * 4;  // codes gid+{0..3,16..19}
            if (m > b1)      { b2 = b1; i2 = i1; b1 = m; i1 = gid; }
            else if (m > b2) { b2 = m;  i2 = gid; }
        }
        #pragma unroll
        for (int o = 16; o <= 32; o <<= 1) {   // merge across the 4 quads
            float c1 = __shfl_xor(b1, o, 64);
            int   j1 = __shfl_xor(i1, o, 64);
            float c2 = __shfl_xor(b2, o, 64);
            int   j2 = __shfl_xor(i2, o, 64);
            if (c1 > b1) {
                b2 = fmaxf(b1, c2); i2 = (b1 >= c2) ? i1 : j2;
                b1 = c1; i1 = j1;
            } else {
                i2 = (b2 >= c1) ? i2 : j1;
                b2 = fmaxf(b2, c1);
            }
        }
        if (quad == 0) {
            int row = row0 + wn * 64 + nj * 16 + l15;
            size_t b = (size_t)row * CPR + (ct * 4 + wm * 2);
            cand_s[b]     = b1;  cand_i[b]     = i1;
            cand_s[b + 1] = b2;  cand_i[b + 1] = i2;
        }
    }
}

// --------- kernel 2: exact fp32 rescore of surviving groups + gather --------
__global__ __launch_bounds__(256) void rescore_kernel(
    const float* __restrict__ x, const float* __restrict__ embed,
    const float* __restrict__ e_sq, const float* __restrict__ f_sq,
    const float* __restrict__ cand_s, const int* __restrict__ cand_i,
    float* __restrict__ out)
{
    int row = blockIdx.x * 4 + (threadIdx.x >> 6);
    int lane = threadIdx.x & 63;
    size_t cb = (size_t)row * CPR;

    float cs0 = cand_s[cb + lane];
    float cs1 = cand_s[cb + 64 + lane];
    int   ci0 = cand_i[cb + lane];
    int   ci1 = cand_i[cb + 64 + lane];

    float m = fmaxf(cs0, cs1);
    #pragma unroll
    for (int o = 32; o >= 1; o >>= 1) m = fmaxf(m, __shfl_xor(m, o, 64));

    unsigned long long mask0 = __ballot(cs0 >= m - MARGIN);
    unsigned long long mask1 = __ballot(cs1 >= m - MARGIN);

    const float4* xsrc = (const float4*)(x + (size_t)row * DIM + lane * 8);
    float4 xa = xsrc[0], xb = xsrc[1];
    float fsq = f_sq[row];

    float bd = NEG_INF;
    int   bi = 0x7fffffff;

    #pragma unroll
    for (int s = 0; s < 2; ++s) {
        unsigned long long mask = s ? mask1 : mask0;
        while (mask) {
            int p = __ffsll(mask) - 1;
            mask &= mask - 1;
            int base = __shfl(s ? ci1 : ci0, p);
            #pragma unroll
            for (int e8 = 0; e8 < 8; ++e8) {
                int c = base + ((e8 >> 2) << 4) + (e8 & 3);  // {0..3, 16..19}
                const float4* er = (const float4*)(embed + (size_t)c * DIM + lane * 8);
                float4 ea = er[0], eb = er[1];
                float part = xa.x*ea.x + xa.y*ea.y + xa.z*ea.z + xa.w*ea.w
                           + xb.x*eb.x + xb.y*eb.y + xb.z*eb.z + xb.w*eb.w;
                #pragma unroll
                for (int o = 32; o >= 1; o >>= 1) part += __shfl_xor(part, o, 64);
                float d = -((fsq - 2.0f * part) + e_sq[c]);   // np rounding order
                if (d > bd || (d == bd && c < bi)) { bd = d; bi = c; }
            }
        }
    }

    const float4* er = (const float4*)(embed + (size_t)bi * DIM + lane * 8);
    float4 qa = er[0], qb = er[1];
    float4* dst = (float4*)(out + (size_t)row * DIM + lane * 8);
    dst[0] = qa; dst[1] = qb;
    if (lane == 0) out[(size_t)NROWS * DIM + row] = (float)bi;
}

extern "C" void kernel_launch(void* const* d_in, const int* in_sizes, int n_in,
                              void* d_out, int out_size, void* d_ws, size_t ws_size,
                              hipStream_t stream)
{
    const float* x     = (const float*)d_in[0];   // [16384, 512] fp32
    const float* embed = (const float*)d_in[1];   // [8192, 512] fp32
    float* out = (float*)d_out;

    // ws layout (~25 MB), all 16B-aligned
    float* e_sq   = (float*)d_ws;                               // 8192
    float* esqh   = e_sq + KCODES;                              // 8192 (-e_sq/2)
    float* f_sq   = esqh + KCODES;                              // 16384
    float* cand_s = f_sq + NROWS;                               // 16384*128
    int*   cand_i = (int*)(cand_s + (size_t)NROWS * CPR);       // 16384*128
    int4*  e_t    = (int4*)(cand_i + (size_t)NROWS * CPR);      // [64][8192] int4 = 8 MB

    // x_t lives in d_out scratch (16 MB of 33.6 MB); rescore overwrites later.
    int4* x_t = (int4*)d_out;

    (void)in_sizes; (void)n_in; (void)out_size; (void)ws_size;

    convert_kernel<<<(KCODES + NROWS) / 64, 256, 0, stream>>>(
        x, embed, e_t, x_t, e_sq, esqh, f_sq);
    screen_kernel<<<2048, 512, 0, stream>>>(
        e_t, x_t, esqh, cand_s, cand_i);
    rescore_kernel<<<NROWS / 4, 256, 0, stream>>>(
        x, embed, e_sq, f_sq, cand_s, cand_i, out);
}